// Round 2
// baseline (471.192 us; speedup 1.0000x reference)
//
#include <hip/hip_runtime.h>
#include <hip/hip_bf16.h>
#include <cstdint>

// Problem dims (fixed by reference setup_inputs)
constexpr int Bc  = 2;
constexpr int Lc  = 4096;
constexpr int Hc  = 2048;
constexpr int LKc = 128;
constexpr float LAMc = 0.003f;

typedef __attribute__((ext_vector_type(8))) __bf16 bf16x8;
typedef __attribute__((ext_vector_type(4))) float  f32x4;
typedef __attribute__((ext_vector_type(2))) float  f32x2;

// ---------------------------------------------------------------------------
// async global->LDS, 16B per lane. LDS dest is wave-uniform base + lane*16.
// ---------------------------------------------------------------------------
__device__ __forceinline__ void gl_lds16(const void* g, void* lds) {
  __builtin_amdgcn_global_load_lds(
      (const __attribute__((address_space(1))) uint32_t*)(uintptr_t)g,
      (__attribute__((address_space(3))) uint32_t*)(uint32_t)(uintptr_t)lds,
      16, 0, 0);
}

// ---------------------------------------------------------------------------
// Kernel 1: squash taps + transpose to kq_t[j*H + h]
// ---------------------------------------------------------------------------
__global__ __launch_bounds__(256) void squash_kernel(
    const float* __restrict__ kin, float* __restrict__ kq) {
  const int idx = blockIdx.x * 256 + threadIdx.x;  // idx = j*H + h
  const int j = idx >> 11;
  const int h = idx & (Hc - 1);
  const float v = kin[h * LKc + j];
  const float a = fabsf(v) - LAMc;
  kq[idx] = (a > 0.f) ? copysignf(a, v) : 0.f;
}

// ---------------------------------------------------------------------------
// Kernel 2: W fp32 [2H, H] -> bf16 same layout
// ---------------------------------------------------------------------------
__global__ __launch_bounds__(256) void wcast_kernel(
    const float* __restrict__ W, __hip_bfloat16* __restrict__ Wb) {
  const int idx = (blockIdx.x * 256 + threadIdx.x) * 4;
  const float4 v = *(const float4*)(W + idx);
  Wb[idx + 0] = __float2bfloat16(v.x);
  Wb[idx + 1] = __float2bfloat16(v.y);
  Wb[idx + 2] = __float2bfloat16(v.z);
  Wb[idx + 3] = __float2bfloat16(v.w);
}

// ---------------------------------------------------------------------------
// Kernel 3: causal 128-tap FIR + 2*D*u skip + exact GELU -> bf16 A[M,H]
// Each lane: h-PAIR (float2 / v_pk_fma_f32), 16 consecutive l outputs,
// register sliding window, FULL unroll (register renaming kills shift movs).
// ---------------------------------------------------------------------------
template <bool CHECK>
__device__ __forceinline__ void conv_accum2(
    const float* __restrict__ ub, const float* __restrict__ kqh,
    const int l0, f32x2 acc[16], f32x2 win[23]) {
#pragma unroll
  for (int x = 0; x < 23; ++x) {
    const int il = l0 - 127 + x;
    win[x] = (!CHECK || il >= 0) ? *(const f32x2*)(ub + (size_t)il * Hc)
                                 : f32x2{0.f, 0.f};
  }
#pragma unroll
  for (int c = 0; c < 15; ++c) {
    f32x2 t[8];
#pragma unroll
    for (int d = 0; d < 8; ++d)
      t[d] = *(const f32x2*)(kqh + (127 - 8 * c - d) * Hc);
#pragma unroll
    for (int d = 0; d < 8; ++d)
#pragma unroll
      for (int i = 0; i < 16; ++i)
        acc[i] = __builtin_elementwise_fma(t[d], win[i + d], acc[i]);
#pragma unroll
    for (int x = 0; x < 15; ++x) win[x] = win[x + 8];
#pragma unroll
    for (int x = 15; x < 23; ++x) {
      const int il = l0 - 127 + 8 * (c + 1) + x;
      win[x] = (!CHECK || il >= 0) ? *(const f32x2*)(ub + (size_t)il * Hc)
                                   : f32x2{0.f, 0.f};
    }
  }
  {  // c = 15: taps j = 7-d; window now u[l0-7 .. l0+15]
    f32x2 t[8];
#pragma unroll
    for (int d = 0; d < 8; ++d) t[d] = *(const f32x2*)(kqh + (7 - d) * Hc);
#pragma unroll
    for (int d = 0; d < 8; ++d)
#pragma unroll
      for (int i = 0; i < 16; ++i)
        acc[i] = __builtin_elementwise_fma(t[d], win[i + d], acc[i]);
  }
}

__global__ __launch_bounds__(256) void conv_gelu_kernel(
    const float* __restrict__ u, const float* __restrict__ kq,
    const float* __restrict__ Dp, __hip_bfloat16* __restrict__ Aout) {
  const int lane = threadIdx.x & 63;
  const int wv   = threadIdx.x >> 6;
  const int h  = blockIdx.y * 128 + lane * 2;   // h-pair per lane
  const int l0 = blockIdx.x * 64 + wv * 16;
  const int b  = blockIdx.z;
  const float* ub  = u + (size_t)b * Lc * Hc + h;
  const float* kqh = kq + h;

  f32x2 acc[16], win[23];
#pragma unroll
  for (int i = 0; i < 16; ++i) acc[i] = f32x2{0.f, 0.f};

  if (blockIdx.x >= 2)
    conv_accum2<false>(ub, kqh, l0, acc, win);
  else
    conv_accum2<true>(ub, kqh, l0, acc, win);

  const f32x2 d2 = *(const f32x2*)(Dp + h);
  const f32x2 dv = f32x2{2.f * d2.x, 2.f * d2.y};  // duplicated skip -> factor 2
  const size_t obase = ((size_t)b * Lc + l0) * (size_t)Hc + h;
#pragma unroll
  for (int i = 0; i < 16; ++i) {
    const f32x2 y = __builtin_elementwise_fma(dv, win[i + 7], acc[i]);
    const float gx = 0.5f * y.x * (1.f + erff(y.x * 0.70710678118654752f));
    const float gy = 0.5f * y.y * (1.f + erff(y.y * 0.70710678118654752f));
    __hip_bfloat162 o;
    o.x = __float2bfloat16(gx);
    o.y = __float2bfloat16(gy);
    *(__hip_bfloat162*)(Aout + obase + (size_t)i * Hc) = o;
  }
}

// ---------------------------------------------------------------------------
// Kernel 4: GEMM + bias + GLU with XOR-swizzled LDS (bank-conflict-free b128).
// LDS row = 32 bf16 (64B) as four 16B k-groups; group g of row r stored at
// slot g ^ ((r>>1)&3). Within any 16-lane phase each 4-bank group start
// appears exactly twice (the b128 minimum) -> conflict-free.
// ---------------------------------------------------------------------------
__device__ __forceinline__ const bf16x8* frag_ptr(
    const __hip_bfloat16* base, int r, int g) {
  return (const bf16x8*)(base + r * 32 + ((g ^ ((r >> 1) & 3)) * 8));
}

__global__ __launch_bounds__(256, 2) void gemm_glu_kernel(
    const __hip_bfloat16* __restrict__ A, const __hip_bfloat16* __restrict__ Wb,
    const float* __restrict__ bias, float* __restrict__ out) {
  __shared__ __align__(16) __hip_bfloat16 As[128 * 32];  // 8 KB
  __shared__ __align__(16) __hip_bfloat16 Bs[128 * 32];  // rows 0..63=a, 64..127=g

  const int t    = threadIdx.x;
  const int lane = t & 63;
  const int wv   = t >> 6;
  const int quad = lane >> 4;
  const int l16  = lane & 15;
  const int m0 = blockIdx.x * 128;
  const int n0 = blockIdx.y * 64;

  f32x4 accA[2][4], accG[2][4];
#pragma unroll
  for (int i = 0; i < 2; ++i)
#pragma unroll
    for (int j = 0; j < 4; ++j) {
      accA[i][j] = f32x4{0.f, 0.f, 0.f, 0.f};
      accG[i][j] = f32x4{0.f, 0.f, 0.f, 0.f};
    }

  // staging: thread t owns LDS slot (row=t>>2, group=t&3); it must FETCH the
  // global k-group gg such that (t&3) == gg ^ ((srow>>1)&3).
  const int srow = t >> 2;
  const int gg   = (t & 3) ^ ((srow >> 1) & 3);
  const int scol = gg * 8;
  const __hip_bfloat16* gA0 = A  + (size_t)(m0 + srow) * Hc + scol;
  const __hip_bfloat16* gA1 = A  + (size_t)(m0 + 64 + srow) * Hc + scol;
  const __hip_bfloat16* gBa = Wb + (size_t)(n0 + srow) * Hc + scol;
  const __hip_bfloat16* gBg = Wb + (size_t)(Hc + n0 + srow) * Hc + scol;
  char* ldsA0 = (char*)As + wv * 1024;
  char* ldsA1 = (char*)As + 4096 + wv * 1024;
  char* ldsBa = (char*)Bs + wv * 1024;
  char* ldsBg = (char*)Bs + 4096 + wv * 1024;

  const bf16x8* ar0 = frag_ptr(As, wv * 32 + l16, quad);
  const bf16x8* ar1 = frag_ptr(As, wv * 32 + 16 + l16, quad);

  for (int it = 0; it < 64; ++it) {
    const int k0 = it * 32;
    gl_lds16(gA0 + k0, ldsA0);
    gl_lds16(gA1 + k0, ldsA1);
    gl_lds16(gBa + k0, ldsBa);
    gl_lds16(gBg + k0, ldsBg);
    __syncthreads();
    const bf16x8 af0 = *ar0;
    const bf16x8 af1 = *ar1;
#pragma unroll
    for (int nj = 0; nj < 4; ++nj) {
      const bf16x8 ba = *frag_ptr(Bs, nj * 16 + l16, quad);
      const bf16x8 bg = *frag_ptr(Bs, 64 + nj * 16 + l16, quad);
      accA[0][nj] = __builtin_amdgcn_mfma_f32_16x16x32_bf16(af0, ba, accA[0][nj], 0, 0, 0);
      accA[1][nj] = __builtin_amdgcn_mfma_f32_16x16x32_bf16(af1, ba, accA[1][nj], 0, 0, 0);
      accG[0][nj] = __builtin_amdgcn_mfma_f32_16x16x32_bf16(af0, bg, accG[0][nj], 0, 0, 0);
      accG[1][nj] = __builtin_amdgcn_mfma_f32_16x16x32_bf16(af1, bg, accG[1][nj], 0, 0, 0);
    }
    __syncthreads();
  }

  // epilogue: C/D layout col = lane&15, row = quad*4 + reg
  const int mbase = m0 + wv * 32;
#pragma unroll
  for (int mi = 0; mi < 2; ++mi) {
#pragma unroll
    for (int nj = 0; nj < 4; ++nj) {
      const int n = n0 + nj * 16 + l16;
      const float ba_ = bias[n];
      const float bg_ = bias[Hc + n];
#pragma unroll
      for (int r = 0; r < 4; ++r) {
        const int m = mbase + mi * 16 + quad * 4 + r;
        const float a = accA[mi][nj][r] + ba_;
        const float g = accG[mi][nj][r] + bg_;
        out[(size_t)m * Hc + n] = a * (1.f / (1.f + __expf(-g)));
      }
    }
  }
}

// ---------------------------------------------------------------------------
extern "C" void kernel_launch(void* const* d_in, const int* in_sizes, int n_in,
                              void* d_out, int out_size, void* d_ws, size_t ws_size,
                              hipStream_t stream) {
  const float* u    = (const float*)d_in[0];  // [B, L, H]
  const float* kin  = (const float*)d_in[1];  // [1, H, LK]
  const float* Dp   = (const float*)d_in[2];  // [1, H]
  const float* W    = (const float*)d_in[3];  // [2H, H]
  const float* bias = (const float*)d_in[4];  // [2H]
  float* out = (float*)d_out;                 // [B, L, H]

  char* ws = (char*)d_ws;
  float*          kq = (float*)ws;                            // LK*H fp32 = 1 MB
  __hip_bfloat16* Wb = (__hip_bfloat16*)(ws + (1 << 20));     // 2H*H bf16 = 16 MB
  __hip_bfloat16* Am = (__hip_bfloat16*)(ws + (17 << 20));    // M*H bf16 = 32 MB

  squash_kernel<<<(Hc * LKc) / 256, 256, 0, stream>>>(kin, kq);
  wcast_kernel<<<(2 * Hc * Hc) / 1024, 256, 0, stream>>>(W, Wb);
  conv_gelu_kernel<<<dim3(Lc / 64, Hc / 128, Bc), 256, 0, stream>>>(u, kq, Dp, Am);
  gemm_glu_kernel<<<dim3((Bc * Lc) / 128, Hc / 64), 256, 0, stream>>>(Am, Wb, bias, out);
}

// Round 3
// 391.702 us; speedup vs baseline: 1.2029x; 1.2029x over previous
//
#include <hip/hip_runtime.h>
#include <hip/hip_bf16.h>
#include <cstdint>

// Problem dims (fixed by reference setup_inputs)
constexpr int Bc  = 2;
constexpr int Lc  = 4096;
constexpr int Hc  = 2048;
constexpr int LKc = 128;
constexpr float LAMc = 0.003f;

typedef __attribute__((ext_vector_type(8))) __bf16 bf16x8;
typedef __attribute__((ext_vector_type(4))) float  f32x4;
typedef __attribute__((ext_vector_type(8))) unsigned short ushort8;

__device__ __forceinline__ unsigned short f2bf_bits(float v) {
  union { __hip_bfloat16 b; unsigned short u; } cv;
  cv.b = __float2bfloat16(v);
  return cv.u;
}

// ---------------------------------------------------------------------------
// async global->LDS, 16B per lane (GEMM staging only)
// ---------------------------------------------------------------------------
__device__ __forceinline__ void gl_lds16(const void* g, void* lds) {
  __builtin_amdgcn_global_load_lds(
      (const __attribute__((address_space(1))) uint32_t*)(uintptr_t)g,
      (__attribute__((address_space(3))) uint32_t*)(uint32_t)(uintptr_t)lds,
      16, 0, 0);
}

// ---------------------------------------------------------------------------
// Kernel 1: tap squash + Hankel MFMA A-fragment precompute.
// Afr[h][cc][lane][jj] (bf16), cc=0..4 <-> c=cc-1:
//   A_c[m][k] = tap_sq[h][m + 32*(cc-1) + k],  m=lane&15, k=8*(lane>>4)+jj
// zero outside j in [0,128).
// ---------------------------------------------------------------------------
__global__ __launch_bounds__(256) void tapfrag_kernel(
    const float* __restrict__ kin, unsigned short* __restrict__ Afr) {
  const int idx  = blockIdx.x * 256 + threadIdx.x;  // [0, 2048*5*64)
  const int lane = idx & 63;
  const int idx2 = idx >> 6;          // h*5 + cc
  const int h  = idx2 / 5;
  const int cc = idx2 - h * 5;
  const int m = lane & 15, quad = lane >> 4;
  const int jb = m + 32 * cc - 32 + 8 * quad;
  ushort8 o;
#pragma unroll
  for (int jj = 0; jj < 8; ++jj) {
    const int j = jb + jj;
    float v = 0.f;
    if (j >= 0 && j < LKc) {
      const float x = kin[h * LKc + j];
      const float a = fabsf(x) - LAMc;
      v = (a > 0.f) ? copysignf(a, x) : 0.f;
    }
    o[jj] = f2bf_bits(v);
  }
  ((ushort8*)Afr)[idx] = o;
}

// ---------------------------------------------------------------------------
// Kernel 2: W fp32 [2H, H] -> bf16 same layout
// ---------------------------------------------------------------------------
__global__ __launch_bounds__(256) void wcast_kernel(
    const float* __restrict__ W, __hip_bfloat16* __restrict__ Wb) {
  const int idx = (blockIdx.x * 256 + threadIdx.x) * 4;
  const float4 v = *(const float4*)(W + idx);
  Wb[idx + 0] = __float2bfloat16(v.x);
  Wb[idx + 1] = __float2bfloat16(v.y);
  Wb[idx + 2] = __float2bfloat16(v.z);
  Wb[idx + 3] = __float2bfloat16(v.w);
}

// ---------------------------------------------------------------------------
// Kernel 3: MFMA-based causal FIR + 2*D*u skip + exact GELU -> bf16 A[M,H].
// Block: 16 h x 256 l for one b. Wave w handles h_loc = 4w..4w+3.
// Per (h, 256 l): 5 MFMAs, D[m][n] = Y[l0 + m + 16 n].
//   B_c[k][n] = u[l0 + 16n - 32(cc-1) - k]  via reversed bf16 LDS window ur
//   ur[x] = u[l0 + 272 - x], x in [0,400)
// uc = fp32 center copy (exact skip term); ot = [l][h] transpose for output.
// ---------------------------------------------------------------------------
__global__ __launch_bounds__(256) void conv_mfma_kernel(
    const float* __restrict__ u, const unsigned short* __restrict__ Afr,
    const float* __restrict__ Dp, unsigned short* __restrict__ Am) {
  __shared__ __align__(16) unsigned short ur[16 * 408];  // reversed bf16 window
  __shared__ __align__(16) float          uc[16 * 260];  // fp32 center copy
  __shared__ __align__(16) unsigned short ot[256 * 17];  // out transpose [l][h]

  const int t    = threadIdx.x;
  const int lane = t & 63;
  const int wv   = t >> 6;
  const int l16  = lane & 15;
  const int quad = lane >> 4;
  const int l0 = blockIdx.x * 256;
  const int h0 = blockIdx.y * 16;
  const int b  = blockIdx.z;

  const size_t ubase = (size_t)b * Lc * Hc + h0;

  // ---- stage: 6400 elements (16 h x 400 l), coalesced (16 h = one 64B line)
#pragma unroll
  for (int i = 0; i < 25; ++i) {
    const int e  = (i << 8) + t;
    const int hl = e & 15;
    const int x  = e >> 4;
    const int l  = l0 + 272 - x;
    float v = 0.f;
    if (l >= 0) v = u[ubase + (size_t)min(l, Lc - 1) * Hc + hl];
    ur[hl * 408 + x] = f2bf_bits(v);
    const int lc = l - l0;
    if (lc >= 0 && lc < 256) uc[hl * 260 + lc] = v;
  }
  __syncthreads();

  // ---- MFMA + epilogue per h
#pragma unroll
  for (int hi = 0; hi < 4; ++hi) {
    const int hl = (wv << 2) | hi;
    const int h  = h0 + hl;
    f32x4 acc = f32x4{0.f, 0.f, 0.f, 0.f};
    const unsigned short* afp = Afr + ((size_t)(h * 5) * 64 + lane) * 8;
    const int bbase = hl * 408 + 240 - 16 * l16 + 8 * quad;
#pragma unroll
    for (int cc = 0; cc < 5; ++cc) {
      const bf16x8 af = *(const bf16x8*)(afp + cc * 512);
      const bf16x8 bf = *(const bf16x8*)(&ur[bbase + 32 * cc]);
      acc = __builtin_amdgcn_mfma_f32_16x16x32_bf16(af, bf, acc, 0, 0, 0);
    }
    // epilogue: lane holds outputs l = l0 + (quad*4 + r) + 16*l16, r=0..3
    const float dv = 2.f * Dp[h];  // duplicated skip line in reference
    const float4 u4 = *(const float4*)(&uc[hl * 260 + quad * 4 + 16 * l16]);
    const float uu[4] = {u4.x, u4.y, u4.z, u4.w};
#pragma unroll
    for (int r = 0; r < 4; ++r) {
      const int lc = quad * 4 + r + 16 * l16;
      const float y = fmaf(dv, uu[r], acc[r]);
      const float g = 0.5f * y * (1.f + erff(y * 0.70710678118654752f));
      ot[lc * 17 + hl] = f2bf_bits(g);
    }
  }
  __syncthreads();

  // ---- coalesced output: thread t writes row lc=t (16 bf16 = 32B)
  {
    const int lc = t;
    const unsigned short* row = &ot[lc * 17];
    unsigned int w[8];
#pragma unroll
    for (int p = 0; p < 8; ++p)
      w[p] = (unsigned int)row[2 * p] | ((unsigned int)row[2 * p + 1] << 16);
    unsigned short* dst = Am + ((size_t)(b * Lc + l0 + lc)) * Hc + h0;
    *(uint4*)(dst)     = make_uint4(w[0], w[1], w[2], w[3]);
    *(uint4*)(dst + 8) = make_uint4(w[4], w[5], w[6], w[7]);
  }
}

// ---------------------------------------------------------------------------
// Kernel 4: GEMM + bias + GLU (round-1 proven version).
// ---------------------------------------------------------------------------
__global__ __launch_bounds__(256, 2) void gemm_glu_kernel(
    const __hip_bfloat16* __restrict__ A, const __hip_bfloat16* __restrict__ Wb,
    const float* __restrict__ bias, float* __restrict__ out) {
  __shared__ __align__(16) __hip_bfloat16 As[128 * 32];  // 8 KB
  __shared__ __align__(16) __hip_bfloat16 Bs[128 * 32];  // rows 0..63=a, 64..127=g

  const int t    = threadIdx.x;
  const int lane = t & 63;
  const int wv   = t >> 6;
  const int quad = lane >> 4;
  const int l16  = lane & 15;
  const int m0 = blockIdx.x * 128;
  const int n0 = blockIdx.y * 64;

  f32x4 accA[2][4], accG[2][4];
#pragma unroll
  for (int i = 0; i < 2; ++i)
#pragma unroll
    for (int j = 0; j < 4; ++j) {
      accA[i][j] = f32x4{0.f, 0.f, 0.f, 0.f};
      accG[i][j] = f32x4{0.f, 0.f, 0.f, 0.f};
    }

  const int srow = t >> 2;
  const int scol = (t & 3) * 8;
  const __hip_bfloat16* gA0 = A  + (size_t)(m0 + srow) * Hc + scol;
  const __hip_bfloat16* gA1 = A  + (size_t)(m0 + 64 + srow) * Hc + scol;
  const __hip_bfloat16* gBa = Wb + (size_t)(n0 + srow) * Hc + scol;
  const __hip_bfloat16* gBg = Wb + (size_t)(Hc + n0 + srow) * Hc + scol;
  char* ldsA0 = (char*)As + wv * 1024;
  char* ldsA1 = (char*)As + 4096 + wv * 1024;
  char* ldsBa = (char*)Bs + wv * 1024;
  char* ldsBg = (char*)Bs + 4096 + wv * 1024;

  const bf16x8* ar0 = (const bf16x8*)(As + (wv * 32 + l16) * 32 + quad * 8);
  const bf16x8* ar1 = (const bf16x8*)(As + (wv * 32 + 16 + l16) * 32 + quad * 8);

  for (int it = 0; it < 64; ++it) {
    const int k0 = it * 32;
    gl_lds16(gA0 + k0, ldsA0);
    gl_lds16(gA1 + k0, ldsA1);
    gl_lds16(gBa + k0, ldsBa);
    gl_lds16(gBg + k0, ldsBg);
    __syncthreads();
    const bf16x8 af0 = *ar0;
    const bf16x8 af1 = *ar1;
#pragma unroll
    for (int nj = 0; nj < 4; ++nj) {
      const bf16x8 ba = *(const bf16x8*)(Bs + (nj * 16 + l16) * 32 + quad * 8);
      const bf16x8 bg = *(const bf16x8*)(Bs + (64 + nj * 16 + l16) * 32 + quad * 8);
      accA[0][nj] = __builtin_amdgcn_mfma_f32_16x16x32_bf16(af0, ba, accA[0][nj], 0, 0, 0);
      accA[1][nj] = __builtin_amdgcn_mfma_f32_16x16x32_bf16(af1, ba, accA[1][nj], 0, 0, 0);
      accG[0][nj] = __builtin_amdgcn_mfma_f32_16x16x32_bf16(af0, bg, accG[0][nj], 0, 0, 0);
      accG[1][nj] = __builtin_amdgcn_mfma_f32_16x16x32_bf16(af1, bg, accG[1][nj], 0, 0, 0);
    }
    __syncthreads();
  }

  const int mbase = m0 + wv * 32;
#pragma unroll
  for (int mi = 0; mi < 2; ++mi) {
#pragma unroll
    for (int nj = 0; nj < 4; ++nj) {
      const int n = n0 + nj * 16 + l16;
      const float ba_ = bias[n];
      const float bg_ = bias[Hc + n];
#pragma unroll
      for (int r = 0; r < 4; ++r) {
        const int m = mbase + mi * 16 + quad * 4 + r;
        const float a = accA[mi][nj][r] + ba_;
        const float g = accG[mi][nj][r] + bg_;
        out[(size_t)m * Hc + n] = a * (1.f / (1.f + expf(-g)));
      }
    }
  }
}

// ---------------------------------------------------------------------------
extern "C" void kernel_launch(void* const* d_in, const int* in_sizes, int n_in,
                              void* d_out, int out_size, void* d_ws, size_t ws_size,
                              hipStream_t stream) {
  const float* u    = (const float*)d_in[0];  // [B, L, H]
  const float* kin  = (const float*)d_in[1];  // [1, H, LK]
  const float* Dp   = (const float*)d_in[2];  // [1, H]
  const float* W    = (const float*)d_in[3];  // [2H, H]
  const float* bias = (const float*)d_in[4];  // [2H]
  float* out = (float*)d_out;                 // [B, L, H]

  // ws layout (48 MB total, proven footprint):
  //   [0, 10.5MB)  Afr  (tap fragments; dead after conv)
  //   [0, 16MB)    Wb   (bf16 W; written AFTER conv reads Afr -- same stream)
  //   [16MB, 48MB) Am   (bf16 activations)
  char* ws = (char*)d_ws;
  unsigned short* Afr = (unsigned short*)ws;
  __hip_bfloat16* Wb  = (__hip_bfloat16*)ws;
  unsigned short* Am  = (unsigned short*)(ws + (16 << 20));

  tapfrag_kernel<<<(Hc * 5 * 64) / 256, 256, 0, stream>>>(kin, Afr);
  conv_mfma_kernel<<<dim3(Lc / 256, Hc / 16, Bc), 256, 0, stream>>>(u, Afr, Dp, Am);
  wcast_kernel<<<(2 * Hc * Hc) / 1024, 256, 0, stream>>>(W, Wb);
  gemm_glu_kernel<<<dim3((Bc * Lc) / 128, Hc / 64), 256, 0, stream>>>(
      (const __hip_bfloat16*)Am, Wb, bias, out);
}

// Round 4
// 376.955 us; speedup vs baseline: 1.2500x; 1.0391x over previous
//
#include <hip/hip_runtime.h>
#include <hip/hip_bf16.h>
#include <cstdint>

// Problem dims (fixed by reference setup_inputs)
constexpr int Bc  = 2;
constexpr int Lc  = 4096;
constexpr int Hc  = 2048;
constexpr int LKc = 128;
constexpr float LAMc = 0.003f;

typedef __attribute__((ext_vector_type(8))) __bf16 bf16x8;
typedef __attribute__((ext_vector_type(4))) float  f32x4;
typedef __attribute__((ext_vector_type(8))) unsigned short ushort8;

__device__ __forceinline__ unsigned short f2bf_bits(float v) {
  union { __hip_bfloat16 b; unsigned short u; } cv;
  cv.b = __float2bfloat16(v);
  return cv.u;
}
__device__ __forceinline__ float bf_bits2f(unsigned short u) {
  union { unsigned int i; float f; } cv;
  cv.i = ((unsigned int)u) << 16;
  return cv.f;
}

// ---------------------------------------------------------------------------
// async global->LDS, 16B per lane (GEMM staging only)
// ---------------------------------------------------------------------------
__device__ __forceinline__ void gl_lds16(const void* g, void* lds) {
  __builtin_amdgcn_global_load_lds(
      (const __attribute__((address_space(1))) uint32_t*)(uintptr_t)g,
      (__attribute__((address_space(3))) uint32_t*)(uint32_t)(uintptr_t)lds,
      16, 0, 0);
}

// ---------------------------------------------------------------------------
// Kernel 1: tap squash + Hankel MFMA A-fragment precompute.
// Afr[h][cc][lane][jj] (bf16), cc=0..4 <-> c=cc-1:
//   A_c[m][k] = tap_sq[h][m + 32*(cc-1) + k],  m=lane&15, k=8*(lane>>4)+jj
// ---------------------------------------------------------------------------
__global__ __launch_bounds__(256) void tapfrag_kernel(
    const float* __restrict__ kin, unsigned short* __restrict__ Afr) {
  const int idx  = blockIdx.x * 256 + threadIdx.x;  // [0, 2048*5*64)
  const int lane = idx & 63;
  const int idx2 = idx >> 6;          // h*5 + cc
  const int h  = idx2 / 5;
  const int cc = idx2 - h * 5;
  const int m = lane & 15, quad = lane >> 4;
  const int jb = m + 32 * cc - 32 + 8 * quad;
  ushort8 o;
#pragma unroll
  for (int jj = 0; jj < 8; ++jj) {
    const int j = jb + jj;
    float v = 0.f;
    if (j >= 0 && j < LKc) {
      const float x = kin[h * LKc + j];
      const float a = fabsf(x) - LAMc;
      v = (a > 0.f) ? copysignf(a, x) : 0.f;
    }
    o[jj] = f2bf_bits(v);
  }
  ((ushort8*)Afr)[idx] = o;
}

// ---------------------------------------------------------------------------
// Kernel 2: W fp32 [2H, H] -> bf16 same layout
// ---------------------------------------------------------------------------
__global__ __launch_bounds__(256) void wcast_kernel(
    const float* __restrict__ W, __hip_bfloat16* __restrict__ Wb) {
  const int idx = (blockIdx.x * 256 + threadIdx.x) * 4;
  const float4 v = *(const float4*)(W + idx);
  Wb[idx + 0] = __float2bfloat16(v.x);
  Wb[idx + 1] = __float2bfloat16(v.y);
  Wb[idx + 2] = __float2bfloat16(v.z);
  Wb[idx + 3] = __float2bfloat16(v.w);
}

// ---------------------------------------------------------------------------
// Kernel 3 (v3): MFMA FIR, 16 h x 512 l per block.
//  - Afr frags loaded ONCE per h, reused across 2 l-tiles (halves Afr traffic)
//  - hi-loop NOT unrolled (VGPR control, no spills)
//  - skip term reads bf16 u from ur (fp32 uc copy dropped)
// ur[hl*664 + x] = bf16(u[l0 + 528 - x]), x in [0,656)
// B frag elem (tile nt, lane l16/quad, cc, jj) at x = 496-256nt-16*l16+8*quad+32*cc+jj
// ---------------------------------------------------------------------------
__global__ __launch_bounds__(256) void conv_mfma_kernel(
    const float* __restrict__ u, const unsigned short* __restrict__ Afr,
    const float* __restrict__ Dp, unsigned short* __restrict__ Am) {
  __shared__ __align__(16) unsigned short ur[16 * 664];  // 21248 B
  __shared__ __align__(16) unsigned short ot[512 * 17];  // 17408 B

  const int t    = threadIdx.x;
  const int lane = t & 63;
  const int wv   = t >> 6;
  const int l16  = lane & 15;
  const int quad = lane >> 4;
  const int l0 = blockIdx.x * 512;
  const int h0 = blockIdx.y * 16;
  const int b  = blockIdx.z;

  const size_t ubase = (size_t)b * Lc * Hc + h0;

  // ---- stage 16 h x 656 l (reversed, bf16); 41*256 == 16*656
#pragma unroll 4
  for (int i = 0; i < 41; ++i) {
    const int e  = (i << 8) + t;
    const int hl = e & 15;
    const int x  = e >> 4;
    const int l  = l0 + 528 - x;
    float v = 0.f;
    if (l >= 0) v = u[ubase + (size_t)min(l, Lc - 1) * Hc + hl];
    ur[hl * 664 + x] = f2bf_bits(v);
  }
  __syncthreads();

  // ---- per h: load 5 frags once, 2 l-tiles of 5 MFMAs + epilogue
#pragma unroll 1
  for (int hi = 0; hi < 4; ++hi) {
    const int hl = (wv << 2) | hi;
    const int h  = h0 + hl;
    bf16x8 af[5];
    const unsigned short* afp = Afr + ((size_t)(h * 5) * 64 + lane) * 8;
#pragma unroll
    for (int cc = 0; cc < 5; ++cc) af[cc] = *(const bf16x8*)(afp + cc * 512);
    const float dv = 2.f * Dp[h];  // duplicated skip line in reference
    const unsigned short* urh = &ur[hl * 664];
#pragma unroll
    for (int nt = 0; nt < 2; ++nt) {
      f32x4 acc = f32x4{0.f, 0.f, 0.f, 0.f};
      const int bbase = 496 - 256 * nt - 16 * l16 + 8 * quad;
#pragma unroll
      for (int cc = 0; cc < 5; ++cc) {
        const bf16x8 bf = *(const bf16x8*)(urh + bbase + 32 * cc);
        acc = __builtin_amdgcn_mfma_f32_16x16x32_bf16(af[cc], bf, acc, 0, 0, 0);
      }
      // lane outputs: lc = quad*4 + r + 16*l16 within tile nt
#pragma unroll
      for (int r = 0; r < 4; ++r) {
        const int lc = quad * 4 + r + 16 * l16;
        const float uu = bf_bits2f(urh[528 - 256 * nt - lc]);  // u[l0+256nt+lc]
        const float y = fmaf(dv, uu, acc[r]);
        const float g = 0.5f * y * (1.f + erff(y * 0.70710678118654752f));
        ot[(nt * 256 + lc) * 17 + hl] = f2bf_bits(g);
      }
    }
  }
  __syncthreads();

  // ---- coalesced-ish output: thread t writes rows t and t+256 (32B each)
#pragma unroll
  for (int rr = 0; rr < 2; ++rr) {
    const int lc = (rr << 8) + t;
    const unsigned short* row = &ot[lc * 17];
    unsigned int w[8];
#pragma unroll
    for (int p = 0; p < 8; ++p)
      w[p] = (unsigned int)row[2 * p] | ((unsigned int)row[2 * p + 1] << 16);
    unsigned short* dst = Am + ((size_t)(b * Lc + l0 + lc)) * Hc + h0;
    *(uint4*)(dst)     = make_uint4(w[0], w[1], w[2], w[3]);
    *(uint4*)(dst + 8) = make_uint4(w[4], w[5], w[6], w[7]);
  }
}

// ---------------------------------------------------------------------------
// Kernel 4: GEMM + bias + GLU (round-1 proven version, FROZEN this round).
// ---------------------------------------------------------------------------
__global__ __launch_bounds__(256, 2) void gemm_glu_kernel(
    const __hip_bfloat16* __restrict__ A, const __hip_bfloat16* __restrict__ Wb,
    const float* __restrict__ bias, float* __restrict__ out) {
  __shared__ __align__(16) __hip_bfloat16 As[128 * 32];  // 8 KB
  __shared__ __align__(16) __hip_bfloat16 Bs[128 * 32];  // rows 0..63=a, 64..127=g

  const int t    = threadIdx.x;
  const int lane = t & 63;
  const int wv   = t >> 6;
  const int quad = lane >> 4;
  const int l16  = lane & 15;
  const int m0 = blockIdx.x * 128;
  const int n0 = blockIdx.y * 64;

  f32x4 accA[2][4], accG[2][4];
#pragma unroll
  for (int i = 0; i < 2; ++i)
#pragma unroll
    for (int j = 0; j < 4; ++j) {
      accA[i][j] = f32x4{0.f, 0.f, 0.f, 0.f};
      accG[i][j] = f32x4{0.f, 0.f, 0.f, 0.f};
    }

  const int srow = t >> 2;
  const int scol = (t & 3) * 8;
  const __hip_bfloat16* gA0 = A  + (size_t)(m0 + srow) * Hc + scol;
  const __hip_bfloat16* gA1 = A  + (size_t)(m0 + 64 + srow) * Hc + scol;
  const __hip_bfloat16* gBa = Wb + (size_t)(n0 + srow) * Hc + scol;
  const __hip_bfloat16* gBg = Wb + (size_t)(Hc + n0 + srow) * Hc + scol;
  char* ldsA0 = (char*)As + wv * 1024;
  char* ldsA1 = (char*)As + 4096 + wv * 1024;
  char* ldsBa = (char*)Bs + wv * 1024;
  char* ldsBg = (char*)Bs + 4096 + wv * 1024;

  const bf16x8* ar0 = (const bf16x8*)(As + (wv * 32 + l16) * 32 + quad * 8);
  const bf16x8* ar1 = (const bf16x8*)(As + (wv * 32 + 16 + l16) * 32 + quad * 8);

  for (int it = 0; it < 64; ++it) {
    const int k0 = it * 32;
    gl_lds16(gA0 + k0, ldsA0);
    gl_lds16(gA1 + k0, ldsA1);
    gl_lds16(gBa + k0, ldsBa);
    gl_lds16(gBg + k0, ldsBg);
    __syncthreads();
    const bf16x8 af0 = *ar0;
    const bf16x8 af1 = *ar1;
#pragma unroll
    for (int nj = 0; nj < 4; ++nj) {
      const bf16x8 ba = *(const bf16x8*)(Bs + (nj * 16 + l16) * 32 + quad * 8);
      const bf16x8 bg = *(const bf16x8*)(Bs + (64 + nj * 16 + l16) * 32 + quad * 8);
      accA[0][nj] = __builtin_amdgcn_mfma_f32_16x16x32_bf16(af0, ba, accA[0][nj], 0, 0, 0);
      accA[1][nj] = __builtin_amdgcn_mfma_f32_16x16x32_bf16(af1, ba, accA[1][nj], 0, 0, 0);
      accG[0][nj] = __builtin_amdgcn_mfma_f32_16x16x32_bf16(af0, bg, accG[0][nj], 0, 0, 0);
      accG[1][nj] = __builtin_amdgcn_mfma_f32_16x16x32_bf16(af1, bg, accG[1][nj], 0, 0, 0);
    }
    __syncthreads();
  }

  const int mbase = m0 + wv * 32;
#pragma unroll
  for (int mi = 0; mi < 2; ++mi) {
#pragma unroll
    for (int nj = 0; nj < 4; ++nj) {
      const int n = n0 + nj * 16 + l16;
      const float ba_ = bias[n];
      const float bg_ = bias[Hc + n];
#pragma unroll
      for (int r = 0; r < 4; ++r) {
        const int m = mbase + mi * 16 + quad * 4 + r;
        const float a = accA[mi][nj][r] + ba_;
        const float g = accG[mi][nj][r] + bg_;
        out[(size_t)m * Hc + n] = a * (1.f / (1.f + expf(-g)));
      }
    }
  }
}

// ---------------------------------------------------------------------------
extern "C" void kernel_launch(void* const* d_in, const int* in_sizes, int n_in,
                              void* d_out, int out_size, void* d_ws, size_t ws_size,
                              hipStream_t stream) {
  const float* u    = (const float*)d_in[0];  // [B, L, H]
  const float* kin  = (const float*)d_in[1];  // [1, H, LK]
  const float* Dp   = (const float*)d_in[2];  // [1, H]
  const float* W    = (const float*)d_in[3];  // [2H, H]
  const float* bias = (const float*)d_in[4];  // [2H]
  float* out = (float*)d_out;                 // [B, L, H]

  // ws layout:
  //   [0, 10.5MB)  Afr  (tap fragments; dead after conv)
  //   [0, 16MB)    Wb   (bf16 W; written AFTER conv reads Afr -- same stream)
  //   [16MB, 48MB) Am   (bf16 activations)
  char* ws = (char*)d_ws;
  unsigned short* Afr = (unsigned short*)ws;
  __hip_bfloat16* Wb  = (__hip_bfloat16*)ws;
  unsigned short* Am  = (unsigned short*)(ws + (16 << 20));

  tapfrag_kernel<<<(Hc * 5 * 64) / 256, 256, 0, stream>>>(kin, Afr);
  conv_mfma_kernel<<<dim3(Lc / 512, Hc / 16, Bc), 256, 0, stream>>>(u, Afr, Dp, Am);
  wcast_kernel<<<(2 * Hc * Hc) / 1024, 256, 0, stream>>>(W, Wb);
  gemm_glu_kernel<<<dim3((Bc * Lc) / 128, Hc / 64), 256, 0, stream>>>(
      (const __hip_bfloat16*)Am, Wb, bias, out);
}